// Round 12
// baseline (194.374 us; speedup 1.0000x reference)
//
#include <hip/hip_runtime.h>

typedef unsigned short u16;
typedef unsigned int   u32;
typedef unsigned long long u64;
typedef __attribute__((ext_vector_type(4))) float f32x4;
typedef __attribute__((ext_vector_type(8))) short bf16x8;
typedef __attribute__((ext_vector_type(4))) u16  u16x4;
typedef __attribute__((ext_vector_type(8))) u16  u16x8;
typedef __attribute__((ext_vector_type(4))) u32  u32x4;
typedef __attribute__((ext_vector_type(4))) int  i32x4;

#define B_  32
#define TQ  1024
#define TK  1024
#define FG  128
#define DV  256

__device__ __forceinline__ u16 f2bf(float x) {
    union { float f; u32 u; } v; v.f = x;
    u32 r = v.u + 0x7fffu + ((v.u >> 16) & 1u);   // RNE
    return (u16)(r >> 16);
}
__device__ __forceinline__ float bf2f(u16 h) {
    union { u32 u; float f; } v; v.u = ((u32)h) << 16;
    return v.f;
}

// ---------------------------------------------------------------------------
// prep_all: 512-thread blocks.
// blocks [0,1024): mask_pack (vectorized int4 + LDS bitmap, no atomics)
// blocks [1024,3072): prep_v ; blocks [3072,3328): prep_w
__global__ __launch_bounds__(512, 4)
void prep_all(const int* __restrict__ mask, u32* __restrict__ mb,
              const float* __restrict__ v, u16* __restrict__ vtf,
              const float* __restrict__ Wq, const float* __restrict__ Wk,
              u16* __restrict__ wqh, u16* __restrict__ wql,
              u16* __restrict__ wkh, u16* __restrict__ wkl)
{
    __shared__ char sm[9216];
    const int blk = blockIdx.x;
    const int tid = threadIdx.x;

    if (blk < 1024) {
        // ---- mask_pack: one 32-row tile per block ----
        u32 (*bitmap)[32] = reinterpret_cast<u32 (*)[32]>(sm);   // [row][colgroup]
        const int b = blk >> 5, qt = blk & 31;
        const int row0 = qt * 32;
        // Stage A: thread t owns row t>>4, cols [64q,64q+64) (q = t&15)
        const int row = tid >> 4, q = tid & 15;
        const int* mrow = mask + ((u64)b * TQ + row0 + row) * TK + q * 64;
        u32 w0 = 0, w1 = 0;
#pragma unroll
        for (int j = 0; j < 8; ++j) {
            i32x4 a = __builtin_nontemporal_load(reinterpret_cast<const i32x4*>(mrow + j * 4));
#pragma unroll
            for (int e = 0; e < 4; ++e) if (a[e] != 0) w0 |= 1u << (j * 4 + e);
        }
#pragma unroll
        for (int j = 0; j < 8; ++j) {
            i32x4 a = __builtin_nontemporal_load(reinterpret_cast<const i32x4*>(mrow + 32 + j * 4));
#pragma unroll
            for (int e = 0; e < 4; ++e) if (a[e] != 0) w1 |= 1u << (j * 4 + e);
        }
        bitmap[row][q * 2]     = w0;
        bitmap[row][q * 2 + 1] = w1;
        __syncthreads();
        // Stage B: per-lane gather into attn's packed layout
        const int wid = tid >> 6, lane = tid & 63;
        const int l16 = lane & 15, l4 = lane >> 4;
        u32 mb0 = 0, mb1 = 0;
#pragma unroll
        for (int mf = 0; mf < 2; ++mf)
#pragma unroll
            for (int r = 0; r < 4; ++r) {
                const int rr = mf * 16 + l4 * 4 + r;
                u32 w[4];
#pragma unroll
                for (int g = 0; g < 4; ++g) w[g] = bitmap[rr][wid * 4 + g];
#pragma unroll
                for (int nf = 0; nf < 8; ++nf) {
                    const u32 bit = (w[nf >> 1] >> ((nf & 1) * 16 + l16)) & 1u;
                    const int idx = mf * 32 + r * 8 + nf;
                    if (idx < 32) mb0 |= bit << idx; else mb1 |= bit << (idx - 32);
                }
            }
        const u64 o = ((u64)(b * 32 + qt) * 512 + tid) * 2;
        mb[o] = mb0; mb[o + 1] = mb1;
    } else if (blk < 3072) {
        // ---- prep_v (512 thr) ----
        u16 (*tile)[72] = reinterpret_cast<u16 (*)[72]>(sm);
        const int idx = blk - 1024;
        const int tk0 = (idx & 15) * 64, d0 = ((idx >> 4) & 3) * 64, b = idx >> 6;
#pragma unroll
        for (int i = 0; i < 2; ++i) {
            const int f4 = i * 512 + tid;
            const int tkr = f4 >> 4, c4 = f4 & 15;
            f32x4 x = *reinterpret_cast<const f32x4*>(v + (u64)b * (TK * DV) + (u64)(tk0 + tkr) * DV + d0 + c4 * 4);
#pragma unroll
            for (int j = 0; j < 4; ++j) tile[tkr][c4 * 4 + j] = f2bf(x[j]);
        }
        __syncthreads();
        {
            const int g_l = tid >> 7, ks_l = (tid >> 6) & 1, lane2 = tid & 63;
            const int l4b = lane2 >> 4, l16b = lane2 & 15;
            const int d_l = g_l * 16 + l16b, kv_l = ks_l * 32 + l4b * 8;
            u16x8 o;
#pragma unroll
            for (int e = 0; e < 8; ++e) o[e] = tile[kv_l + e][d_l];
            const u64 flat = (((u64)(b * 16 + (d0 >> 4) + g_l) * 32 + (tk0 >> 5) + ks_l) * 64 + lane2) * 8;
            *reinterpret_cast<u16x8*>(vtf + flat) = o;
        }
    } else {
        // ---- prep_w (512 thr) ----
        const int t = (blk - 3072) * 512 + tid;
        if (t < 65536) {
            const int k = t >> 7, n = t & 127;
            const float x = Wq[t];
            const u16 h = f2bf(x);
            const int colg = n >> 4, l16 = n & 15, ck = k >> 5, l4 = (k >> 3) & 3, e = k & 7;
            const int flat = (((colg * 16 + ck) * 4 + l4) * 16 + l16) * 8 + e;  // CK=16
            wqh[flat] = h; wql[flat] = f2bf(x - bf2f(h));
        } else if (t < 98304) {
            const int u = t - 65536;
            const int k = u >> 7, n = u & 127;
            const float x = Wk[u];
            const u16 h = f2bf(x);
            const int colg = n >> 4, l16 = n & 15, ck = k >> 5, l4 = (k >> 3) & 3, e = k & 7;
            const int flat = (((colg * 8 + ck) * 4 + l4) * 16 + l16) * 8 + e;   // CK=8
            wkh[flat] = h; wkl[flat] = f2bf(x - bf2f(h));
        }
    }
}

// ---------------------------------------------------------------------------
// proj_all: q-projection (blocks <1024) and k-projection in one launch.
// kp_lo is never consumed by attn (2-term QK^T) -> skip its global store.
__global__ __launch_bounds__(256, 6)
void proj_all(const float* __restrict__ q, const float* __restrict__ kin,
              const u16* __restrict__ wqh, const u16* __restrict__ wql,
              const u16* __restrict__ wkh, const u16* __restrict__ wkl,
              u16* __restrict__ qph, u16* __restrict__ qpl,
              u16* __restrict__ kph)
{
    __shared__ char qs[16384];
    char* qsh = qs;
    char* qsl = qs + 8192;
    const int tid = threadIdx.x;
    const int wid = tid >> 6, lane = tid & 63;
    const int l16 = lane & 15, l4 = lane >> 4;
    const int wm = wid >> 1, wn = wid & 1;

    const int isQ = blockIdx.x < 1024;
    const float* X = isQ ? q : kin;
    const u16* WfH = isQ ? wqh : wkh;
    const u16* WfL = isQ ? wql : wkl;
    u16* Ofh = isQ ? qph : kph;
    const int K = isQ ? 512 : 256;
    const int CK = isQ ? 16 : 8;
    const float scale = isQ ? 0.0625f : 1.0f;
    const int rowbase = (isQ ? blockIdx.x : blockIdx.x - 1024) * 32;

    f32x4 acc[4] = {};
    const int nchunks = K >> 7;
    for (int kc = 0; kc < nchunks; ++kc) {
        if (kc) __syncthreads();
#pragma unroll
        for (int i = 0; i < 4; ++i) {
            const int f4 = i * 256 + tid;
            const int r = f4 >> 5, c4 = f4 & 31;
            f32x4 x = *reinterpret_cast<const f32x4*>(X + (u64)(rowbase + r) * K + kc * 128 + c4 * 4);
            u16x4 hv, lv;
#pragma unroll
            for (int j = 0; j < 4; ++j) {
                const u16 h = f2bf(x[j]);
                hv[j] = h;
                lv[j] = f2bf(x[j] - bf2f(h));
            }
            const u32 a = r * 256 + ((u32)(c4 * 8) ^ ((r & 7) << 4));
            *reinterpret_cast<u16x4*>(qsh + a) = hv;
            *reinterpret_cast<u16x4*>(qsl + a) = lv;
        }
        __syncthreads();
#pragma unroll
        for (int kk = 0; kk < 4; ++kk) {
            const int r = wm * 16 + l16;
            const u32 kb = kk * 64 + l4 * 16;
            const u32 a = r * 256 + (kb ^ ((u32)(r & 7) << 4));
            bf16x8 ah = *reinterpret_cast<const bf16x8*>(qsh + a);
            bf16x8 al = *reinterpret_cast<const bf16x8*>(qsl + a);
#pragma unroll
            for (int nf = 0; nf < 4; ++nf) {
                const u64 off = ((u64)((wn * 4 + nf) * CK + kc * 4 + kk)) * 512 + lane * 8;
                bf16x8 bh = *reinterpret_cast<const bf16x8*>(WfH + off);
                bf16x8 bl = *reinterpret_cast<const bf16x8*>(WfL + off);
                acc[nf] = __builtin_amdgcn_mfma_f32_16x16x32_bf16(ah, bh, acc[nf], 0, 0, 0);
                acc[nf] = __builtin_amdgcn_mfma_f32_16x16x32_bf16(ah, bl, acc[nf], 0, 0, 0);
                acc[nf] = __builtin_amdgcn_mfma_f32_16x16x32_bf16(al, bh, acc[nf], 0, 0, 0);
            }
        }
    }
    // ---- epilogue: scale+split -> LDS -> fragment-order stores ----
    __syncthreads();
#pragma unroll
    for (int nf = 0; nf < 4; ++nf)
#pragma unroll
        for (int r = 0; r < 4; ++r) {
            const int tok = wm * 16 + l4 * 4 + r;
            const int fg  = wn * 64 + nf * 16 + l16;
            const float xv = acc[nf][r] * scale;
            const u16 h = f2bf(xv);
            const u32 a = tok * 256 + ((u32)(fg * 2) ^ ((tok & 7) << 4));
            *reinterpret_cast<u16*>(qsh + a) = h;
            *reinterpret_cast<u16*>(qsl + a) = f2bf(xv - bf2f(h));
        }
    __syncthreads();
#pragma unroll
    for (int pass = 0; pass < 2; ++pass) {
        const int idx = pass * 256 + tid;        // [tokg_l(2)][kk(4)][lane(64)]
        const int tokg_l = idx >> 8, kk2 = (idx >> 6) & 3, lane2 = idx & 63;
        const int l4b = lane2 >> 4, l16b = lane2 & 15;
        const int tok = tokg_l * 16 + l16b;
        const u32 fgb = (u32)(kk2 * 64 + l4b * 16);
        const u32 a = tok * 256 + (fgb ^ ((u32)(tok & 7) << 4));
        u16x8 vh = *reinterpret_cast<const u16x8*>(qsh + a);
        const u64 flat = ((u64)(((rowbase >> 4) + tokg_l) * 4 + kk2) * 64 + lane2) * 8;
        *reinterpret_cast<u16x8*>(Ofh + flat) = vh;
        if (isQ) {
            u16x8 vl = *reinterpret_cast<const u16x8*>(qsl + a);
            *reinterpret_cast<u16x8*>(qpl + flat) = vl;
        }
    }
}

// ---------------------------------------------------------------------------
// attn_fused (R10): no max-shift softmax, full-line NT attn stores.
// 32 Q-rows/block, 1D grid 1024 XCD-swizzled, 512 thr.
__global__ __launch_bounds__(512, 3)
void attn_fused(const u16* __restrict__ qpf_h, const u16* __restrict__ qpf_l,
                const u16* __restrict__ kpf_h, const u16* __restrict__ vtf,
                const u32* __restrict__ mb,
                float* __restrict__ attn_out, float* __restrict__ ctx_out)
{
    extern __shared__ char smem[];
    char* as_ = smem;                                 // P bf16 [32][1024] swizzled, 64KB
    float* red  = (float*)(smem + 65536);             // [8][32]
    float* zrec = red + 256;                          // [0..31] = 1/Z

    const int lin = blockIdx.x;
    const int xcd = lin & 7;
    const int slot = lin >> 3;                        // 0..127
    const int b = xcd * 4 + (slot >> 5);
    const int qt = slot & 31;

    const int row0 = qt * 32;
    const int tid = threadIdx.x;
    const int wid = tid >> 6;
    const int lane = tid & 63;
    const int l16 = lane & 15;
    const int l4  = lane >> 4;

    const u64 mo = ((u64)(b * 32 + qt) * 512 + tid) * 2;
    const u32 mb0 = mb[mo], mb1 = mb[mo + 1];

    // ---- QK^T: 2-term split-bf16, fragment loads 16B/lane coalesced ----
    f32x4 acc[2][8] = {};
    const int qtg = b * 64 + qt * 2;
#pragma unroll
    for (int kk = 0; kk < 4; ++kk) {
        bf16x8 ah[2], al[2];
#pragma unroll
        for (int mf = 0; mf < 2; ++mf) {
            const u64 o = ((u64)((qtg + mf) * 4 + kk) * 64 + lane) * 8;
            ah[mf] = *reinterpret_cast<const bf16x8*>(qpf_h + o);
            al[mf] = *reinterpret_cast<const bf16x8*>(qpf_l + o);
        }
        bf16x8 bh[8];
#pragma unroll
        for (int nf = 0; nf < 8; ++nf) {
            const int colg = b * 64 + wid * 8 + nf;
            bh[nf] = *reinterpret_cast<const bf16x8*>(kpf_h + ((u64)(colg * 4 + kk) * 64 + lane) * 8);
        }
        __builtin_amdgcn_s_setprio(1);
#pragma unroll
        for (int nf = 0; nf < 8; ++nf)
#pragma unroll
            for (int mf = 0; mf < 2; ++mf) {
                acc[mf][nf] = __builtin_amdgcn_mfma_f32_16x16x32_bf16(ah[mf], bh[nf], acc[mf][nf], 0, 0, 0);
                acc[mf][nf] = __builtin_amdgcn_mfma_f32_16x16x32_bf16(al[mf], bh[nf], acc[mf][nf], 0, 0, 0);
            }
        __builtin_amdgcn_s_setprio(0);
    }

    // ---- mask + exp + row sum (no max-shift) ----
#pragma unroll
    for (int mf = 0; mf < 2; ++mf)
#pragma unroll
        for (int r = 0; r < 4; ++r) {
            const int row = mf * 16 + l4 * 4 + r;
            float s = 0.0f;
#pragma unroll
            for (int nf = 0; nf < 8; ++nf) {
                const int idx = mf * 32 + r * 8 + nf;
                const u32 bit = (idx < 32) ? (mb0 >> idx) : (mb1 >> (idx - 32));
                const float e = (bit & 1) ? __expf(acc[mf][nf][r]) : 0.0f;
                acc[mf][nf][r] = e;
                s += e;
            }
#pragma unroll
            for (int sh = 1; sh < 16; sh <<= 1) s += __shfl_xor(s, sh);
            if (l16 == 0) red[wid * 32 + row] = s;
        }
    __syncthreads();
    if (tid < 32) {
        float z = red[tid];
#pragma unroll
        for (int w = 1; w < 8; ++w) z += red[w * 32 + tid];
        zrec[tid] = 1.0f / z;
    }
    __syncthreads();

    // ---- normalize -> bf16 into swizzled LDS P-tile ----
#pragma unroll
    for (int mf = 0; mf < 2; ++mf)
#pragma unroll
        for (int r = 0; r < 4; ++r) {
            const int row = mf * 16 + l4 * 4 + r;
            const float rz = zrec[row];
#pragma unroll
            for (int nf = 0; nf < 8; ++nf) {
                const int col = wid * 128 + nf * 16 + l16;
                const u32 cb = (u32)(col * 2);
                *reinterpret_cast<u16*>(as_ + row * 2048 + (cb ^ ((u32)(row & 7) << 4))) =
                    f2bf(acc[mf][nf][r] * rz);
            }
        }
    __syncthreads();

    // ---- PV with full-line NT attn-write chunks interleaved ----
    f32x4 acc2[2][2] = {};
    float* aout = attn_out + ((u64)b * TQ + row0) * TK;
    for (int grp = 0; grp < 8; ++grp) {
        __builtin_amdgcn_s_setprio(1);
#pragma unroll
        for (int ki = 0; ki < 4; ++ki) {
            const int ks = grp * 4 + ki;
            bf16x8 pa[2];
#pragma unroll
            for (int mf = 0; mf < 2; ++mf) {
                const int r = mf * 16 + l16;
                const u32 kb = ks * 64 + l4 * 16;
                pa[mf] = *reinterpret_cast<const bf16x8*>(as_ + r * 2048 + (kb ^ ((u32)(r & 7) << 4)));
            }
#pragma unroll
            for (int nf2 = 0; nf2 < 2; ++nf2) {
                const int g = b * 16 + wid * 2 + nf2;
                bf16x8 bv = *reinterpret_cast<const bf16x8*>(vtf + ((u64)(g * 32 + ks) * 64 + lane) * 8);
#pragma unroll
                for (int mf = 0; mf < 2; ++mf)
                    acc2[mf][nf2] = __builtin_amdgcn_mfma_f32_16x16x32_bf16(pa[mf], bv, acc2[mf][nf2], 0, 0, 0);
            }
        }
        __builtin_amdgcn_s_setprio(0);
        // two full-line chunks: f32x4 per lane, wave = 1KB contiguous
#pragma unroll
        for (int c = 0; c < 2; ++c) {
            const int it = grp * 2 + c;               // 0..15
            const int flat4 = it * 2048 + tid * 4;
            const int row = flat4 >> 10, col = flat4 & 1023;
            u16x4 p4 = *reinterpret_cast<const u16x4*>(as_ + row * 2048 + (((u32)(col * 2)) ^ ((u32)(row & 7) << 4)));
            f32x4 o;
#pragma unroll
            for (int j = 0; j < 4; ++j) o[j] = bf2f(p4[j]);
            __builtin_nontemporal_store(o, reinterpret_cast<f32x4*>(aout + (u64)row * TK + col));
        }
    }

    // ---- ctx: normal stores ----
    float* cout = ctx_out + ((u64)b * TQ + row0) * DV;
#pragma unroll
    for (int mf = 0; mf < 2; ++mf)
#pragma unroll
        for (int nf2 = 0; nf2 < 2; ++nf2)
#pragma unroll
            for (int r = 0; r < 4; ++r) {
                const int row = mf * 16 + l4 * 4 + r;
                const int d = wid * 32 + nf2 * 16 + l16;
                cout[(u64)row * DV + d] = acc2[mf][nf2][r];
            }
}

// ---------------------------------------------------------------------------
extern "C" void kernel_launch(void* const* d_in, const int* in_sizes, int n_in,
                              void* d_out, int out_size, void* d_ws, size_t ws_size,
                              hipStream_t stream)
{
    const float* q    = (const float*)d_in[0];
    const float* k    = (const float*)d_in[1];
    const float* v    = (const float*)d_in[2];
    const int*   mask = (const int*)d_in[3];
    const float* Wq   = (const float*)d_in[4];
    const float* Wk   = (const float*)d_in[5];

    float* ctx  = (float*)d_out;
    float* attn = ctx + (u64)B_ * TQ * DV;

    u16* p = (u16*)d_ws;
    u16* qpf_h = p; p += (u64)B_ * TQ * FG;
    u16* qpf_l = p; p += (u64)B_ * TQ * FG;
    u16* kpf_h = p; p += (u64)B_ * TK * FG;
    u16* kpf_l = p; p += (u64)B_ * TK * FG;   // unused (2-term QK^T), kept for layout
    u16* vtf   = p; p += (u64)B_ * DV * TK;
    u16* wqf_h = p; p += 128 * 512;
    u16* wqf_l = p; p += 128 * 512;
    u16* wkf_h = p; p += 128 * 256;
    u16* wkf_l = p; p += 128 * 256;
    u32* mb  = (u32*)p;   // 4 MB packed mask
    (void)kpf_l;

    hipLaunchKernelGGL(prep_all, dim3(3328), dim3(512), 0, stream,
                       mask, mb, v, vtf, Wq, Wk, wqf_h, wqf_l, wkf_h, wkf_l);
    hipLaunchKernelGGL(proj_all, dim3(2048), dim3(256), 0, stream,
                       q, k, wqf_h, wqf_l, wkf_h, wkf_l, qpf_h, qpf_l, kpf_h);

    const int lds = 65536 + 256 * 4 + 32 * 4;
    (void)hipFuncSetAttribute(reinterpret_cast<const void*>(attn_fused),
                              hipFuncAttributeMaxDynamicSharedMemorySize, lds);
    hipLaunchKernelGGL(attn_fused, dim3(1024), dim3(512), lds, stream,
                       qpf_h, qpf_l, kpf_h, vtf, mb, attn, ctx);
}

// Round 13
// 156.965 us; speedup vs baseline: 1.2383x; 1.2383x over previous
//
#include <hip/hip_runtime.h>

typedef unsigned short u16;
typedef unsigned int   u32;
typedef unsigned long long u64;
typedef __attribute__((ext_vector_type(4))) float f32x4;
typedef __attribute__((ext_vector_type(8))) short bf16x8;
typedef __attribute__((ext_vector_type(4))) u16  u16x4;
typedef __attribute__((ext_vector_type(8))) u16  u16x8;
typedef __attribute__((ext_vector_type(4))) u32  u32x4;

#define B_  32
#define TQ  1024
#define TK  1024
#define FG  128
#define DV  256

__device__ __forceinline__ u16 f2bf(float x) {
    union { float f; u32 u; } v; v.f = x;
    u32 r = v.u + 0x7fffu + ((v.u >> 16) & 1u);   // RNE
    return (u16)(r >> 16);
}
__device__ __forceinline__ float bf2f(u16 h) {
    union { u32 u; float f; } v; v.u = ((u32)h) << 16;
    return v.f;
}

// ---------------------------------------------------------------------------
// prep_all (R11-measured): one launch for all independent prep work.
// blocks [0,2048): mask_pack ; [2048,4096): prep_v ; [4096,4480): prep_w
// Mask loads: scalar NT, 16 consecutive lanes cover contiguous 64B per instr
// (spatial coalescing) — DO NOT convert to per-lane-contiguous int4+NT (R12
// regression: NT defeats the temporal line reuse that pattern needs).
__global__ __launch_bounds__(256, 4)
void prep_all(const int* __restrict__ mask, u32* __restrict__ mb,
              const float* __restrict__ v, u16* __restrict__ vtf,
              const float* __restrict__ Wq, const float* __restrict__ Wk,
              u16* __restrict__ wqh, u16* __restrict__ wql,
              u16* __restrict__ wkh, u16* __restrict__ wkl)
{
    __shared__ u16 tile[64][72];
    const int blk = blockIdx.x;
    const int tid = threadIdx.x;

    if (blk < 2048) {
        // ---- mask_pack (NT scalar loads, read-once 128MB) ----
        const int half = blk & 1;
        const int qt = (blk >> 1) & 31;
        const int b = blk >> 6;
        const int row0 = qt * 32;
        const int tid2 = half * 256 + tid;
        const int wid = tid2 >> 6, lane = tid2 & 63;
        const int l16 = lane & 15, l4 = lane >> 4;
        const int* mrow = mask + ((u64)b * TQ + row0) * TK;
        u32 mb0 = 0, mb1 = 0;
#pragma unroll
        for (int mf = 0; mf < 2; ++mf)
#pragma unroll
            for (int r = 0; r < 4; ++r) {
                const int row = mf * 16 + l4 * 4 + r;
#pragma unroll
                for (int nf = 0; nf < 8; ++nf) {
                    const int col = wid * 128 + nf * 16 + l16;
                    const int idx = mf * 32 + r * 8 + nf;
                    const int mv = __builtin_nontemporal_load(mrow + (u64)row * TK + col);
                    const u32 bit = (mv != 0) ? 1u : 0u;
                    if (idx < 32) mb0 |= bit << idx; else mb1 |= bit << (idx - 32);
                }
            }
        const u64 o = ((u64)(b * 32 + qt) * 512 + tid2) * 2;
        mb[o] = mb0; mb[o + 1] = mb1;
    } else if (blk < 4096) {
        // ---- prep_v ----
        const int idx = blk - 2048;
        const int tk0 = (idx & 15) * 64, d0 = ((idx >> 4) & 3) * 64, b = idx >> 6;
#pragma unroll
        for (int i = 0; i < 4; ++i) {
            const int f4 = i * 256 + tid;
            const int tkr = f4 >> 4, c4 = f4 & 15;
            f32x4 x = *reinterpret_cast<const f32x4*>(v + (u64)b * (TK * DV) + (u64)(tk0 + tkr) * DV + d0 + c4 * 4);
#pragma unroll
            for (int j = 0; j < 4; ++j) tile[tkr][c4 * 4 + j] = f2bf(x[j]);
        }
        __syncthreads();
#pragma unroll
        for (int pass = 0; pass < 2; ++pass) {
            const int idx2 = pass * 256 + tid;
            const int g_l = idx2 >> 7, ks_l = (idx2 >> 6) & 1, lane2 = idx2 & 63;
            const int l4b = lane2 >> 4, l16b = lane2 & 15;
            const int d_l = g_l * 16 + l16b, kv_l = ks_l * 32 + l4b * 8;
            u16x8 o;
#pragma unroll
            for (int e = 0; e < 8; ++e) o[e] = tile[kv_l + e][d_l];
            const u64 flat = (((u64)(b * 16 + (d0 >> 4) + g_l) * 32 + (tk0 >> 5) + ks_l) * 64 + lane2) * 8;
            *reinterpret_cast<u16x8*>(vtf + flat) = o;
        }
    } else {
        // ---- prep_w ----
        const int t = (blk - 4096) * 256 + tid;
        if (t < 65536) {
            const int k = t >> 7, n = t & 127;
            const float x = Wq[t];
            const u16 h = f2bf(x);
            const int colg = n >> 4, l16 = n & 15, ck = k >> 5, l4 = (k >> 3) & 3, e = k & 7;
            const int flat = (((colg * 16 + ck) * 4 + l4) * 16 + l16) * 8 + e;  // CK=16
            wqh[flat] = h; wql[flat] = f2bf(x - bf2f(h));
        } else {
            const int u = t - 65536;
            const int k = u >> 7, n = u & 127;
            const float x = Wk[u];
            const u16 h = f2bf(x);
            const int colg = n >> 4, l16 = n & 15, ck = k >> 5, l4 = (k >> 3) & 3, e = k & 7;
            const int flat = (((colg * 8 + ck) * 4 + l4) * 16 + l16) * 8 + e;   // CK=8
            wkh[flat] = h; wkl[flat] = f2bf(x - bf2f(h));
        }
    }
}

// ---------------------------------------------------------------------------
// proj_all: q-projection (blocks <1024) and k-projection in one launch.
// kp_lo is never consumed by attn (2-term QK^T) -> skip its global store.
__global__ __launch_bounds__(256, 6)
void proj_all(const float* __restrict__ q, const float* __restrict__ kin,
              const u16* __restrict__ wqh, const u16* __restrict__ wql,
              const u16* __restrict__ wkh, const u16* __restrict__ wkl,
              u16* __restrict__ qph, u16* __restrict__ qpl,
              u16* __restrict__ kph)
{
    __shared__ char qs[16384];
    char* qsh = qs;
    char* qsl = qs + 8192;
    const int tid = threadIdx.x;
    const int wid = tid >> 6, lane = tid & 63;
    const int l16 = lane & 15, l4 = lane >> 4;
    const int wm = wid >> 1, wn = wid & 1;

    const int isQ = blockIdx.x < 1024;
    const float* X = isQ ? q : kin;
    const u16* WfH = isQ ? wqh : wkh;
    const u16* WfL = isQ ? wql : wkl;
    u16* Ofh = isQ ? qph : kph;
    const int K = isQ ? 512 : 256;
    const int CK = isQ ? 16 : 8;
    const float scale = isQ ? 0.0625f : 1.0f;
    const int rowbase = (isQ ? blockIdx.x : blockIdx.x - 1024) * 32;

    f32x4 acc[4] = {};
    const int nchunks = K >> 7;
    for (int kc = 0; kc < nchunks; ++kc) {
        if (kc) __syncthreads();
#pragma unroll
        for (int i = 0; i < 4; ++i) {
            const int f4 = i * 256 + tid;
            const int r = f4 >> 5, c4 = f4 & 31;
            f32x4 x = *reinterpret_cast<const f32x4*>(X + (u64)(rowbase + r) * K + kc * 128 + c4 * 4);
            u16x4 hv, lv;
#pragma unroll
            for (int j = 0; j < 4; ++j) {
                const u16 h = f2bf(x[j]);
                hv[j] = h;
                lv[j] = f2bf(x[j] - bf2f(h));
            }
            const u32 a = r * 256 + ((u32)(c4 * 8) ^ ((r & 7) << 4));
            *reinterpret_cast<u16x4*>(qsh + a) = hv;
            *reinterpret_cast<u16x4*>(qsl + a) = lv;
        }
        __syncthreads();
#pragma unroll
        for (int kk = 0; kk < 4; ++kk) {
            const int r = wm * 16 + l16;
            const u32 kb = kk * 64 + l4 * 16;
            const u32 a = r * 256 + (kb ^ ((u32)(r & 7) << 4));
            bf16x8 ah = *reinterpret_cast<const bf16x8*>(qsh + a);
            bf16x8 al = *reinterpret_cast<const bf16x8*>(qsl + a);
#pragma unroll
            for (int nf = 0; nf < 4; ++nf) {
                const u64 off = ((u64)((wn * 4 + nf) * CK + kc * 4 + kk)) * 512 + lane * 8;
                bf16x8 bh = *reinterpret_cast<const bf16x8*>(WfH + off);
                bf16x8 bl = *reinterpret_cast<const bf16x8*>(WfL + off);
                acc[nf] = __builtin_amdgcn_mfma_f32_16x16x32_bf16(ah, bh, acc[nf], 0, 0, 0);
                acc[nf] = __builtin_amdgcn_mfma_f32_16x16x32_bf16(ah, bl, acc[nf], 0, 0, 0);
                acc[nf] = __builtin_amdgcn_mfma_f32_16x16x32_bf16(al, bh, acc[nf], 0, 0, 0);
            }
        }
    }
    // ---- epilogue: scale+split -> LDS -> fragment-order stores ----
    __syncthreads();
#pragma unroll
    for (int nf = 0; nf < 4; ++nf)
#pragma unroll
        for (int r = 0; r < 4; ++r) {
            const int tok = wm * 16 + l4 * 4 + r;
            const int fg  = wn * 64 + nf * 16 + l16;
            const float xv = acc[nf][r] * scale;
            const u16 h = f2bf(xv);
            const u32 a = tok * 256 + ((u32)(fg * 2) ^ ((tok & 7) << 4));
            *reinterpret_cast<u16*>(qsh + a) = h;
            *reinterpret_cast<u16*>(qsl + a) = f2bf(xv - bf2f(h));
        }
    __syncthreads();
#pragma unroll
    for (int pass = 0; pass < 2; ++pass) {
        const int idx = pass * 256 + tid;        // [tokg_l(2)][kk(4)][lane(64)]
        const int tokg_l = idx >> 8, kk2 = (idx >> 6) & 3, lane2 = idx & 63;
        const int l4b = lane2 >> 4, l16b = lane2 & 15;
        const int tok = tokg_l * 16 + l16b;
        const u32 fgb = (u32)(kk2 * 64 + l4b * 16);
        const u32 a = tok * 256 + (fgb ^ ((u32)(tok & 7) << 4));
        u16x8 vh = *reinterpret_cast<const u16x8*>(qsh + a);
        const u64 flat = ((u64)(((rowbase >> 4) + tokg_l) * 4 + kk2) * 64 + lane2) * 8;
        *reinterpret_cast<u16x8*>(Ofh + flat) = vh;
        if (isQ) {
            u16x8 vl = *reinterpret_cast<const u16x8*>(qsl + a);
            *reinterpret_cast<u16x8*>(qpl + flat) = vl;
        }
    }
}

// ---------------------------------------------------------------------------
// attn_fused (R10-measured): no max-shift softmax, full-line NT attn stores.
// 32 Q-rows/block, 1D grid 1024 XCD-swizzled, 512 thr.
__global__ __launch_bounds__(512, 3)
void attn_fused(const u16* __restrict__ qpf_h, const u16* __restrict__ qpf_l,
                const u16* __restrict__ kpf_h, const u16* __restrict__ vtf,
                const u32* __restrict__ mb,
                float* __restrict__ attn_out, float* __restrict__ ctx_out)
{
    extern __shared__ char smem[];
    char* as_ = smem;                                 // P bf16 [32][1024] swizzled, 64KB
    float* red  = (float*)(smem + 65536);             // [8][32]
    float* zrec = red + 256;                          // [0..31] = 1/Z

    const int lin = blockIdx.x;
    const int xcd = lin & 7;
    const int slot = lin >> 3;                        // 0..127
    const int b = xcd * 4 + (slot >> 5);
    const int qt = slot & 31;

    const int row0 = qt * 32;
    const int tid = threadIdx.x;
    const int wid = tid >> 6;
    const int lane = tid & 63;
    const int l16 = lane & 15;
    const int l4  = lane >> 4;

    const u64 mo = ((u64)(b * 32 + qt) * 512 + tid) * 2;
    const u32 mb0 = mb[mo], mb1 = mb[mo + 1];

    // ---- QK^T: 2-term split-bf16, fragment loads 16B/lane coalesced ----
    f32x4 acc[2][8] = {};
    const int qtg = b * 64 + qt * 2;
#pragma unroll
    for (int kk = 0; kk < 4; ++kk) {
        bf16x8 ah[2], al[2];
#pragma unroll
        for (int mf = 0; mf < 2; ++mf) {
            const u64 o = ((u64)((qtg + mf) * 4 + kk) * 64 + lane) * 8;
            ah[mf] = *reinterpret_cast<const bf16x8*>(qpf_h + o);
            al[mf] = *reinterpret_cast<const bf16x8*>(qpf_l + o);
        }
        bf16x8 bh[8];
#pragma unroll
        for (int nf = 0; nf < 8; ++nf) {
            const int colg = b * 64 + wid * 8 + nf;
            bh[nf] = *reinterpret_cast<const bf16x8*>(kpf_h + ((u64)(colg * 4 + kk) * 64 + lane) * 8);
        }
        __builtin_amdgcn_s_setprio(1);
#pragma unroll
        for (int nf = 0; nf < 8; ++nf)
#pragma unroll
            for (int mf = 0; mf < 2; ++mf) {
                acc[mf][nf] = __builtin_amdgcn_mfma_f32_16x16x32_bf16(ah[mf], bh[nf], acc[mf][nf], 0, 0, 0);
                acc[mf][nf] = __builtin_amdgcn_mfma_f32_16x16x32_bf16(al[mf], bh[nf], acc[mf][nf], 0, 0, 0);
            }
        __builtin_amdgcn_s_setprio(0);
    }

    // ---- mask + exp + row sum (no max-shift) ----
#pragma unroll
    for (int mf = 0; mf < 2; ++mf)
#pragma unroll
        for (int r = 0; r < 4; ++r) {
            const int row = mf * 16 + l4 * 4 + r;
            float s = 0.0f;
#pragma unroll
            for (int nf = 0; nf < 8; ++nf) {
                const int idx = mf * 32 + r * 8 + nf;
                const u32 bit = (idx < 32) ? (mb0 >> idx) : (mb1 >> (idx - 32));
                const float e = (bit & 1) ? __expf(acc[mf][nf][r]) : 0.0f;
                acc[mf][nf][r] = e;
                s += e;
            }
#pragma unroll
            for (int sh = 1; sh < 16; sh <<= 1) s += __shfl_xor(s, sh);
            if (l16 == 0) red[wid * 32 + row] = s;
        }
    __syncthreads();
    if (tid < 32) {
        float z = red[tid];
#pragma unroll
        for (int w = 1; w < 8; ++w) z += red[w * 32 + tid];
        zrec[tid] = 1.0f / z;
    }
    __syncthreads();

    // ---- normalize -> bf16 into swizzled LDS P-tile ----
#pragma unroll
    for (int mf = 0; mf < 2; ++mf)
#pragma unroll
        for (int r = 0; r < 4; ++r) {
            const int row = mf * 16 + l4 * 4 + r;
            const float rz = zrec[row];
#pragma unroll
            for (int nf = 0; nf < 8; ++nf) {
                const int col = wid * 128 + nf * 16 + l16;
                const u32 cb = (u32)(col * 2);
                *reinterpret_cast<u16*>(as_ + row * 2048 + (cb ^ ((u32)(row & 7) << 4))) =
                    f2bf(acc[mf][nf][r] * rz);
            }
        }
    __syncthreads();

    // ---- PV with full-line NT attn-write chunks interleaved ----
    f32x4 acc2[2][2] = {};
    float* aout = attn_out + ((u64)b * TQ + row0) * TK;
    for (int grp = 0; grp < 8; ++grp) {
        __builtin_amdgcn_s_setprio(1);
#pragma unroll
        for (int ki = 0; ki < 4; ++ki) {
            const int ks = grp * 4 + ki;
            bf16x8 pa[2];
#pragma unroll
            for (int mf = 0; mf < 2; ++mf) {
                const int r = mf * 16 + l16;
                const u32 kb = ks * 64 + l4 * 16;
                pa[mf] = *reinterpret_cast<const bf16x8*>(as_ + r * 2048 + (kb ^ ((u32)(r & 7) << 4)));
            }
#pragma unroll
            for (int nf2 = 0; nf2 < 2; ++nf2) {
                const int g = b * 16 + wid * 2 + nf2;
                bf16x8 bv = *reinterpret_cast<const bf16x8*>(vtf + ((u64)(g * 32 + ks) * 64 + lane) * 8);
#pragma unroll
                for (int mf = 0; mf < 2; ++mf)
                    acc2[mf][nf2] = __builtin_amdgcn_mfma_f32_16x16x32_bf16(pa[mf], bv, acc2[mf][nf2], 0, 0, 0);
            }
        }
        __builtin_amdgcn_s_setprio(0);
        // two full-line chunks: f32x4 per lane, wave = 1KB contiguous
#pragma unroll
        for (int c = 0; c < 2; ++c) {
            const int it = grp * 2 + c;               // 0..15
            const int flat4 = it * 2048 + tid * 4;
            const int row = flat4 >> 10, col = flat4 & 1023;
            u16x4 p4 = *reinterpret_cast<const u16x4*>(as_ + row * 2048 + (((u32)(col * 2)) ^ ((u32)(row & 7) << 4)));
            f32x4 o;
#pragma unroll
            for (int j = 0; j < 4; ++j) o[j] = bf2f(p4[j]);
            __builtin_nontemporal_store(o, reinterpret_cast<f32x4*>(aout + (u64)row * TK + col));
        }
    }

    // ---- ctx: normal stores ----
    float* cout = ctx_out + ((u64)b * TQ + row0) * DV;
#pragma unroll
    for (int mf = 0; mf < 2; ++mf)
#pragma unroll
        for (int nf2 = 0; nf2 < 2; ++nf2)
#pragma unroll
            for (int r = 0; r < 4; ++r) {
                const int row = mf * 16 + l4 * 4 + r;
                const int d = wid * 32 + nf2 * 16 + l16;
                cout[(u64)row * DV + d] = acc2[mf][nf2][r];
            }
}

// ---------------------------------------------------------------------------
extern "C" void kernel_launch(void* const* d_in, const int* in_sizes, int n_in,
                              void* d_out, int out_size, void* d_ws, size_t ws_size,
                              hipStream_t stream)
{
    const float* q    = (const float*)d_in[0];
    const float* k    = (const float*)d_in[1];
    const float* v    = (const float*)d_in[2];
    const int*   mask = (const int*)d_in[3];
    const float* Wq   = (const float*)d_in[4];
    const float* Wk   = (const float*)d_in[5];

    float* ctx  = (float*)d_out;
    float* attn = ctx + (u64)B_ * TQ * DV;

    u16* p = (u16*)d_ws;
    u16* qpf_h = p; p += (u64)B_ * TQ * FG;
    u16* qpf_l = p; p += (u64)B_ * TQ * FG;
    u16* kpf_h = p; p += (u64)B_ * TK * FG;
    u16* kpf_l = p; p += (u64)B_ * TK * FG;   // unused (2-term QK^T), kept for layout
    u16* vtf   = p; p += (u64)B_ * DV * TK;
    u16* wqf_h = p; p += 128 * 512;
    u16* wqf_l = p; p += 128 * 512;
    u16* wkf_h = p; p += 128 * 256;
    u16* wkf_l = p; p += 128 * 256;
    u32* mb  = (u32*)p;   // 4 MB packed mask
    (void)kpf_l;

    hipLaunchKernelGGL(prep_all, dim3(4480), dim3(256), 0, stream,
                       mask, mb, v, vtf, Wq, Wk, wqf_h, wqf_l, wkf_h, wkf_l);
    hipLaunchKernelGGL(proj_all, dim3(2048), dim3(256), 0, stream,
                       q, k, wqf_h, wqf_l, wkf_h, wkf_l, qpf_h, qpf_l, kpf_h);

    const int lds = 65536 + 256 * 4 + 32 * 4;
    (void)hipFuncSetAttribute(reinterpret_cast<const void*>(attn_fused),
                              hipFuncAttributeMaxDynamicSharedMemorySize, lds);
    hipLaunchKernelGGL(attn_fused, dim3(1024), dim3(512), lds, stream,
                       qpf_h, qpf_l, kpf_h, vtf, mb, attn, ctx);
}

// Round 14
// 148.298 us; speedup vs baseline: 1.3107x; 1.0584x over previous
//
#include <hip/hip_runtime.h>

typedef unsigned short u16;
typedef unsigned int   u32;
typedef unsigned long long u64;
typedef __attribute__((ext_vector_type(4))) float f32x4;
typedef __attribute__((ext_vector_type(8))) short bf16x8;
typedef __attribute__((ext_vector_type(4))) u16  u16x4;
typedef __attribute__((ext_vector_type(8))) u16  u16x8;
typedef __attribute__((ext_vector_type(4))) u32  u32x4;

#define B_  32
#define TQ  1024
#define TK  1024
#define FG  128
#define DV  256

__device__ __forceinline__ u16 f2bf(float x) {
    union { float f; u32 u; } v; v.f = x;
    u32 r = v.u + 0x7fffu + ((v.u >> 16) & 1u);   // RNE
    return (u16)(r >> 16);
}
__device__ __forceinline__ float bf2f(u16 h) {
    union { u32 u; float f; } v; v.u = ((u32)h) << 16;
    return v.f;
}

// ---------------------------------------------------------------------------
// prep_all (R11-measured): one launch for all independent prep work.
// blocks [0,2048): mask_pack ; [2048,4096): prep_v ; [4096,4480): prep_w
// Mask loads: scalar NT, 16 consecutive lanes cover contiguous 64B per instr
// (spatial coalescing) — DO NOT convert to per-lane-contiguous int4+NT (R12
// regression: NT defeats the temporal line reuse that pattern needs).
__global__ __launch_bounds__(256, 4)
void prep_all(const int* __restrict__ mask, u32* __restrict__ mb,
              const float* __restrict__ v, u16* __restrict__ vtf,
              const float* __restrict__ Wq, const float* __restrict__ Wk,
              u16* __restrict__ wqh, u16* __restrict__ wql,
              u16* __restrict__ wkh, u16* __restrict__ wkl)
{
    __shared__ u16 tile[64][72];
    const int blk = blockIdx.x;
    const int tid = threadIdx.x;

    if (blk < 2048) {
        // ---- mask_pack (NT scalar loads, read-once 128MB) ----
        const int half = blk & 1;
        const int qt = (blk >> 1) & 31;
        const int b = blk >> 6;
        const int row0 = qt * 32;
        const int tid2 = half * 256 + tid;
        const int wid = tid2 >> 6, lane = tid2 & 63;
        const int l16 = lane & 15, l4 = lane >> 4;
        const int* mrow = mask + ((u64)b * TQ + row0) * TK;
        u32 mb0 = 0, mb1 = 0;
#pragma unroll
        for (int mf = 0; mf < 2; ++mf)
#pragma unroll
            for (int r = 0; r < 4; ++r) {
                const int row = mf * 16 + l4 * 4 + r;
#pragma unroll
                for (int nf = 0; nf < 8; ++nf) {
                    const int col = wid * 128 + nf * 16 + l16;
                    const int idx = mf * 32 + r * 8 + nf;
                    const int mv = __builtin_nontemporal_load(mrow + (u64)row * TK + col);
                    const u32 bit = (mv != 0) ? 1u : 0u;
                    if (idx < 32) mb0 |= bit << idx; else mb1 |= bit << (idx - 32);
                }
            }
        const u64 o = ((u64)(b * 32 + qt) * 512 + tid2) * 2;
        mb[o] = mb0; mb[o + 1] = mb1;
    } else if (blk < 4096) {
        // ---- prep_v ----
        const int idx = blk - 2048;
        const int tk0 = (idx & 15) * 64, d0 = ((idx >> 4) & 3) * 64, b = idx >> 6;
#pragma unroll
        for (int i = 0; i < 4; ++i) {
            const int f4 = i * 256 + tid;
            const int tkr = f4 >> 4, c4 = f4 & 15;
            f32x4 x = *reinterpret_cast<const f32x4*>(v + (u64)b * (TK * DV) + (u64)(tk0 + tkr) * DV + d0 + c4 * 4);
#pragma unroll
            for (int j = 0; j < 4; ++j) tile[tkr][c4 * 4 + j] = f2bf(x[j]);
        }
        __syncthreads();
#pragma unroll
        for (int pass = 0; pass < 2; ++pass) {
            const int idx2 = pass * 256 + tid;
            const int g_l = idx2 >> 7, ks_l = (idx2 >> 6) & 1, lane2 = idx2 & 63;
            const int l4b = lane2 >> 4, l16b = lane2 & 15;
            const int d_l = g_l * 16 + l16b, kv_l = ks_l * 32 + l4b * 8;
            u16x8 o;
#pragma unroll
            for (int e = 0; e < 8; ++e) o[e] = tile[kv_l + e][d_l];
            const u64 flat = (((u64)(b * 16 + (d0 >> 4) + g_l) * 32 + (tk0 >> 5) + ks_l) * 64 + lane2) * 8;
            *reinterpret_cast<u16x8*>(vtf + flat) = o;
        }
    } else {
        // ---- prep_w ----
        const int t = (blk - 4096) * 256 + tid;
        if (t < 65536) {
            const int k = t >> 7, n = t & 127;
            const float x = Wq[t];
            const u16 h = f2bf(x);
            const int colg = n >> 4, l16 = n & 15, ck = k >> 5, l4 = (k >> 3) & 3, e = k & 7;
            const int flat = (((colg * 16 + ck) * 4 + l4) * 16 + l16) * 8 + e;  // CK=16
            wqh[flat] = h; wql[flat] = f2bf(x - bf2f(h));
        } else {
            const int u = t - 65536;
            const int k = u >> 7, n = u & 127;
            const float x = Wk[u];
            const u16 h = f2bf(x);
            const int colg = n >> 4, l16 = n & 15, ck = k >> 5, l4 = (k >> 3) & 3, e = k & 7;
            const int flat = (((colg * 8 + ck) * 4 + l4) * 16 + l16) * 8 + e;   // CK=8
            wkh[flat] = h; wkl[flat] = f2bf(x - bf2f(h));
        }
    }
}

// ---------------------------------------------------------------------------
// proj_all: q-projection (blocks <1024) and k-projection in one launch.
// kp_lo is never consumed by attn (2-term QK^T) -> skip its global store.
__global__ __launch_bounds__(256, 6)
void proj_all(const float* __restrict__ q, const float* __restrict__ kin,
              const u16* __restrict__ wqh, const u16* __restrict__ wql,
              const u16* __restrict__ wkh, const u16* __restrict__ wkl,
              u16* __restrict__ qph, u16* __restrict__ qpl,
              u16* __restrict__ kph)
{
    __shared__ char qs[16384];
    char* qsh = qs;
    char* qsl = qs + 8192;
    const int tid = threadIdx.x;
    const int wid = tid >> 6, lane = tid & 63;
    const int l16 = lane & 15, l4 = lane >> 4;
    const int wm = wid >> 1, wn = wid & 1;

    const int isQ = blockIdx.x < 1024;
    const float* X = isQ ? q : kin;
    const u16* WfH = isQ ? wqh : wkh;
    const u16* WfL = isQ ? wql : wkl;
    u16* Ofh = isQ ? qph : kph;
    const int K = isQ ? 512 : 256;
    const int CK = isQ ? 16 : 8;
    const float scale = isQ ? 0.0625f : 1.0f;
    const int rowbase = (isQ ? blockIdx.x : blockIdx.x - 1024) * 32;

    f32x4 acc[4] = {};
    const int nchunks = K >> 7;
    for (int kc = 0; kc < nchunks; ++kc) {
        if (kc) __syncthreads();
#pragma unroll
        for (int i = 0; i < 4; ++i) {
            const int f4 = i * 256 + tid;
            const int r = f4 >> 5, c4 = f4 & 31;
            f32x4 x = *reinterpret_cast<const f32x4*>(X + (u64)(rowbase + r) * K + kc * 128 + c4 * 4);
            u16x4 hv, lv;
#pragma unroll
            for (int j = 0; j < 4; ++j) {
                const u16 h = f2bf(x[j]);
                hv[j] = h;
                lv[j] = f2bf(x[j] - bf2f(h));
            }
            const u32 a = r * 256 + ((u32)(c4 * 8) ^ ((r & 7) << 4));
            *reinterpret_cast<u16x4*>(qsh + a) = hv;
            *reinterpret_cast<u16x4*>(qsl + a) = lv;
        }
        __syncthreads();
#pragma unroll
        for (int kk = 0; kk < 4; ++kk) {
            const int r = wm * 16 + l16;
            const u32 kb = kk * 64 + l4 * 16;
            const u32 a = r * 256 + (kb ^ ((u32)(r & 7) << 4));
            bf16x8 ah = *reinterpret_cast<const bf16x8*>(qsh + a);
            bf16x8 al = *reinterpret_cast<const bf16x8*>(qsl + a);
#pragma unroll
            for (int nf = 0; nf < 4; ++nf) {
                const u64 off = ((u64)((wn * 4 + nf) * CK + kc * 4 + kk)) * 512 + lane * 8;
                bf16x8 bh = *reinterpret_cast<const bf16x8*>(WfH + off);
                bf16x8 bl = *reinterpret_cast<const bf16x8*>(WfL + off);
                acc[nf] = __builtin_amdgcn_mfma_f32_16x16x32_bf16(ah, bh, acc[nf], 0, 0, 0);
                acc[nf] = __builtin_amdgcn_mfma_f32_16x16x32_bf16(ah, bl, acc[nf], 0, 0, 0);
                acc[nf] = __builtin_amdgcn_mfma_f32_16x16x32_bf16(al, bh, acc[nf], 0, 0, 0);
            }
        }
    }
    // ---- epilogue: scale+split -> LDS -> fragment-order stores ----
    __syncthreads();
#pragma unroll
    for (int nf = 0; nf < 4; ++nf)
#pragma unroll
        for (int r = 0; r < 4; ++r) {
            const int tok = wm * 16 + l4 * 4 + r;
            const int fg  = wn * 64 + nf * 16 + l16;
            const float xv = acc[nf][r] * scale;
            const u16 h = f2bf(xv);
            const u32 a = tok * 256 + ((u32)(fg * 2) ^ ((tok & 7) << 4));
            *reinterpret_cast<u16*>(qsh + a) = h;
            *reinterpret_cast<u16*>(qsl + a) = f2bf(xv - bf2f(h));
        }
    __syncthreads();
#pragma unroll
    for (int pass = 0; pass < 2; ++pass) {
        const int idx = pass * 256 + tid;        // [tokg_l(2)][kk(4)][lane(64)]
        const int tokg_l = idx >> 8, kk2 = (idx >> 6) & 3, lane2 = idx & 63;
        const int l4b = lane2 >> 4, l16b = lane2 & 15;
        const int tok = tokg_l * 16 + l16b;
        const u32 fgb = (u32)(kk2 * 64 + l4b * 16);
        const u32 a = tok * 256 + (fgb ^ ((u32)(tok & 7) << 4));
        u16x8 vh = *reinterpret_cast<const u16x8*>(qsh + a);
        const u64 flat = ((u64)(((rowbase >> 4) + tokg_l) * 4 + kk2) * 64 + lane2) * 8;
        *reinterpret_cast<u16x8*>(Ofh + flat) = vh;
        if (isQ) {
            u16x8 vl = *reinterpret_cast<const u16x8*>(qsl + a);
            *reinterpret_cast<u16x8*>(qpl + flat) = vl;
        }
    }
}

// ---------------------------------------------------------------------------
// attn_fused: QK^T in two column-halves (acc[2][4], 32 AGPR) -> peak regs
// ~118 -> 4 waves/SIMD -> 2 blocks/CU. P stored UNNORMALIZED (e^s, no
// max-shift); 1/Z folded into attn readback and ctx epilogue. Full-line NT
// attn stores. 32 Q-rows/block, 1D grid 1024 XCD-swizzled, 512 thr.
__global__ __launch_bounds__(512, 4)
void attn_fused(const u16* __restrict__ qpf_h, const u16* __restrict__ qpf_l,
                const u16* __restrict__ kpf_h, const u16* __restrict__ vtf,
                const u32* __restrict__ mb,
                float* __restrict__ attn_out, float* __restrict__ ctx_out)
{
    extern __shared__ char smem[];
    char* as_ = smem;                                 // P bf16 [32][1024] swizzled, 64KB
    float* red  = (float*)(smem + 65536);             // [8][32]
    float* zrec = red + 256;                          // [0..31] = 1/Z

    const int lin = blockIdx.x;
    const int xcd = lin & 7;
    const int slot = lin >> 3;                        // 0..127
    const int b = xcd * 4 + (slot >> 5);
    const int qt = slot & 31;

    const int row0 = qt * 32;
    const int tid = threadIdx.x;
    const int wid = tid >> 6;
    const int lane = tid & 63;
    const int l16 = lane & 15;
    const int l4  = lane >> 4;

    const u64 mo = ((u64)(b * 32 + qt) * 512 + tid) * 2;
    const u32 mb0 = mb[mo], mb1 = mb[mo + 1];

    // ---- QK^T in two column-halves; e^s (unnormalized) -> LDS ----
    float ssum[2][4] = {};
    const int qtg = b * 64 + qt * 2;
#pragma unroll
    for (int half = 0; half < 2; ++half) {
        f32x4 acc[2][4] = {};
#pragma unroll
        for (int kk = 0; kk < 4; ++kk) {
            bf16x8 ah[2], al[2];
#pragma unroll
            for (int mf = 0; mf < 2; ++mf) {
                const u64 o = ((u64)((qtg + mf) * 4 + kk) * 64 + lane) * 8;
                ah[mf] = *reinterpret_cast<const bf16x8*>(qpf_h + o);
                al[mf] = *reinterpret_cast<const bf16x8*>(qpf_l + o);
            }
            bf16x8 bh[4];
#pragma unroll
            for (int nf = 0; nf < 4; ++nf) {
                const int colg = b * 64 + wid * 8 + half * 4 + nf;
                bh[nf] = *reinterpret_cast<const bf16x8*>(kpf_h + ((u64)(colg * 4 + kk) * 64 + lane) * 8);
            }
            __builtin_amdgcn_s_setprio(1);
#pragma unroll
            for (int nf = 0; nf < 4; ++nf)
#pragma unroll
                for (int mf = 0; mf < 2; ++mf) {
                    acc[mf][nf] = __builtin_amdgcn_mfma_f32_16x16x32_bf16(ah[mf], bh[nf], acc[mf][nf], 0, 0, 0);
                    acc[mf][nf] = __builtin_amdgcn_mfma_f32_16x16x32_bf16(al[mf], bh[nf], acc[mf][nf], 0, 0, 0);
                }
            __builtin_amdgcn_s_setprio(0);
        }
        // mask + exp (no max-shift) + partial row sums + LDS P-write (e^s)
#pragma unroll
        for (int mf = 0; mf < 2; ++mf)
#pragma unroll
            for (int r = 0; r < 4; ++r) {
                const int row = mf * 16 + l4 * 4 + r;
#pragma unroll
                for (int nf = 0; nf < 4; ++nf) {
                    const int idx = mf * 32 + r * 8 + half * 4 + nf;
                    const u32 bit = (idx < 32) ? (mb0 >> idx) : (mb1 >> (idx - 32));
                    const float e = (bit & 1) ? __expf(acc[mf][nf][r]) : 0.0f;
                    ssum[mf][r] += e;
                    const int col = wid * 128 + (half * 4 + nf) * 16 + l16;
                    const u32 cb = (u32)(col * 2);
                    *reinterpret_cast<u16*>(as_ + row * 2048 + (cb ^ ((u32)(row & 7) << 4))) = f2bf(e);
                }
            }
    }

    // ---- row-sum reduce: 16-lane shuffle, cross-wave via LDS ----
#pragma unroll
    for (int mf = 0; mf < 2; ++mf)
#pragma unroll
        for (int r = 0; r < 4; ++r) {
            float s = ssum[mf][r];
#pragma unroll
            for (int sh = 1; sh < 16; sh <<= 1) s += __shfl_xor(s, sh);
            if (l16 == 0) red[wid * 32 + mf * 16 + l4 * 4 + r] = s;
        }
    __syncthreads();
    if (tid < 32) {
        float z = red[tid];
#pragma unroll
        for (int w = 1; w < 8; ++w) z += red[w * 32 + tid];
        zrec[tid] = 1.0f / z;
    }
    __syncthreads();

    // ---- PV on unnormalized P, with full-line NT attn-write interleaved ----
    f32x4 acc2[2][2] = {};
    float* aout = attn_out + ((u64)b * TQ + row0) * TK;
    for (int grp = 0; grp < 8; ++grp) {
        __builtin_amdgcn_s_setprio(1);
#pragma unroll
        for (int ki = 0; ki < 4; ++ki) {
            const int ks = grp * 4 + ki;
            bf16x8 pa[2];
#pragma unroll
            for (int mf = 0; mf < 2; ++mf) {
                const int r = mf * 16 + l16;
                const u32 kb = ks * 64 + l4 * 16;
                pa[mf] = *reinterpret_cast<const bf16x8*>(as_ + r * 2048 + (kb ^ ((u32)(r & 7) << 4)));
            }
#pragma unroll
            for (int nf2 = 0; nf2 < 2; ++nf2) {
                const int g = b * 16 + wid * 2 + nf2;
                bf16x8 bv = *reinterpret_cast<const bf16x8*>(vtf + ((u64)(g * 32 + ks) * 64 + lane) * 8);
#pragma unroll
                for (int mf = 0; mf < 2; ++mf)
                    acc2[mf][nf2] = __builtin_amdgcn_mfma_f32_16x16x32_bf16(pa[mf], bv, acc2[mf][nf2], 0, 0, 0);
            }
        }
        __builtin_amdgcn_s_setprio(0);
        // two full-line chunks: f32x4 per lane, wave = 1KB contiguous; x 1/Z here
#pragma unroll
        for (int c = 0; c < 2; ++c) {
            const int it = grp * 2 + c;               // 0..15
            const int flat4 = it * 2048 + tid * 4;
            const int row = flat4 >> 10, col = flat4 & 1023;
            const float rz = zrec[row];
            u16x4 p4 = *reinterpret_cast<const u16x4*>(as_ + row * 2048 + (((u32)(col * 2)) ^ ((u32)(row & 7) << 4)));
            f32x4 o;
#pragma unroll
            for (int j = 0; j < 4; ++j) o[j] = bf2f(p4[j]) * rz;
            __builtin_nontemporal_store(o, reinterpret_cast<f32x4*>(aout + (u64)row * TK + col));
        }
    }

    // ---- ctx: normal stores, x 1/Z ----
    float* cout = ctx_out + ((u64)b * TQ + row0) * DV;
#pragma unroll
    for (int mf = 0; mf < 2; ++mf)
#pragma unroll
        for (int nf2 = 0; nf2 < 2; ++nf2)
#pragma unroll
            for (int r = 0; r < 4; ++r) {
                const int row = mf * 16 + l4 * 4 + r;
                const int d = wid * 32 + nf2 * 16 + l16;
                cout[(u64)row * DV + d] = acc2[mf][nf2][r] * zrec[row];
            }
}

// ---------------------------------------------------------------------------
extern "C" void kernel_launch(void* const* d_in, const int* in_sizes, int n_in,
                              void* d_out, int out_size, void* d_ws, size_t ws_size,
                              hipStream_t stream)
{
    const float* q    = (const float*)d_in[0];
    const float* k    = (const float*)d_in[1];
    const float* v    = (const float*)d_in[2];
    const int*   mask = (const int*)d_in[3];
    const float* Wq   = (const float*)d_in[4];
    const float* Wk   = (const float*)d_in[5];

    float* ctx  = (float*)d_out;
    float* attn = ctx + (u64)B_ * TQ * DV;

    u16* p = (u16*)d_ws;
    u16* qpf_h = p; p += (u64)B_ * TQ * FG;
    u16* qpf_l = p; p += (u64)B_ * TQ * FG;
    u16* kpf_h = p; p += (u64)B_ * TK * FG;
    u16* kpf_l = p; p += (u64)B_ * TK * FG;   // unused (2-term QK^T), kept for layout
    u16* vtf   = p; p += (u64)B_ * DV * TK;
    u16* wqf_h = p; p += 128 * 512;
    u16* wqf_l = p; p += 128 * 512;
    u16* wkf_h = p; p += 128 * 256;
    u16* wkf_l = p; p += 128 * 256;
    u32* mb  = (u32*)p;   // 4 MB packed mask
    (void)kpf_l;

    hipLaunchKernelGGL(prep_all, dim3(4480), dim3(256), 0, stream,
                       mask, mb, v, vtf, Wq, Wk, wqf_h, wqf_l, wkf_h, wkf_l);
    hipLaunchKernelGGL(proj_all, dim3(2048), dim3(256), 0, stream,
                       q, k, wqf_h, wqf_l, wkf_h, wkf_l, qpf_h, qpf_l, kpf_h);

    const int lds = 65536 + 256 * 4 + 32 * 4;
    (void)hipFuncSetAttribute(reinterpret_cast<const void*>(attn_fused),
                              hipFuncAttributeMaxDynamicSharedMemorySize, lds);
    hipLaunchKernelGGL(attn_fused, dim3(1024), dim3(512), lds, stream,
                       qpf_h, qpf_l, kpf_h, vtf, mb, attn, ctx);
}